// Round 5
// baseline (155.709 us; speedup 1.0000x reference)
//
#include <hip/hip_runtime.h>
#include <math.h>

// Problem constants (B derived at launch; spatial dims fixed by weight shapes).
#define HH 1024
#define WW 1024
#define N1 262144   // 512*512 per-image level-1 detail size
#define N2 65536    // 256*256
#define N3 16384    // 128*128
// Round-5 change: NCHUNK 4 -> 2. Weight traffic = NCHUNK * 12.4 MB (round-2
// proved caches do NOT dedupe the re-reads): 50 -> 25 MB; fwd total 114 -> 89
// MB -> 14.1 us floor. Occupancy drops to 1 block/CU (1 wave/SIMD), but the
// kernel stays BW-bound: per-CU HBM share ~10.6 B/cyc serializes a 32 KB
// image-iter over ~3100 cyc >> ~900 cyc load latency (8 KB/wave in flight,
// unroll-2 overlaps iterations).
#define NCHUNK 2
#define MAX_IPC 8          // LDS sizing bound for fwd's fold stage

#define C_INV_SQRT2 0.70710678118654752440f

static __device__ __forceinline__ void haar_fwd(float P, float Q, float R, float S,
                                                float& a, float& h, float& v, float& d) {
    // reference: split along -1 (cols) first, then -2 (rows)
    const float C = C_INV_SQRT2;
    float lo0 = (P + Q) * C, lo1 = (R + S) * C;
    float hi0 = (P - Q) * C, hi1 = (R - S) * C;
    a = (lo0 + lo1) * C; h = (lo0 - lo1) * C;
    v = (hi0 + hi1) * C; d = (hi0 - hi1) * C;
}

static __device__ __forceinline__ void haar_inv(float a, float h, float v, float d,
                                                float& P, float& Q, float& R, float& S) {
    // reference: merge along -2 (rows) first, then -1 (cols)
    // P=(r0,c0) Q=(r0,c1) R=(r1,c0) S=(r1,c1)
    const float C = C_INV_SQRT2;
    float elo = (a + h) * C, olo = (a - h) * C;
    float ehi = (v + d) * C, ohi = (v - d) * C;
    P = (elo + ehi) * C; Q = (elo - ehi) * C;
    R = (olo + ohi) * C; S = (olo - ohi) * C;
}

// ---------------------------------------------------------------------------
// Kernel 1: forward DWT + logit partials, batch-amortized weights (verified
// round-0 compute body; round-4 LDS fold + channel-major partial).
// Grid: (128 strips, NCHUNK); 256 threads. Thread t owns pixel cols
// [4t,4t+4) x 8 rows: every global load is 64 lanes x contiguous 16B = full
// 1KB lines. Strip weights live in registers, reused across the image loop.
// partial[b][c][strip], channel layout: [0]=approx, [1..3]=lvl3(Wd1),
// [4..6]=lvl2(Wd2), [7..9]=lvl1(Wd3).
// ---------------------------------------------------------------------------
__global__ __launch_bounds__(256) void wa_fwd_dots(
    const float* __restrict__ x,
    const float* __restrict__ Wa,
    const float* __restrict__ Wd1,   // [3*N3, 3] coarsest
    const float* __restrict__ Wd2,   // [3*N2, 3]
    const float* __restrict__ Wd3,   // [3*N1, 3] finest
    float* __restrict__ partial,     // [B, 10, 128] channel-major
    int ipc)                         // images per chunk
{
    const int strip = blockIdx.x;          // [0,128): pixel rows strip*8..+8
    const int chunk = blockIdx.y;
    const int t = threadIdx.x;             // L2-col index; px cols 4t..4t+3
    const int lane = t & 63, wave = t >> 6;

    __shared__ float sm[MAX_IPC][4][10];   // [image][wave][channel]

    // ---- strip weights -> registers (once per block, reused ipc times) ----
    // L1 (Wd3): rows strip*4+qr, cols 2t,2t+1; 6 floats per stream per row.
    float w1[3][4][6];
    #pragma unroll
    for (int qr = 0; qr < 4; ++qr) {
        const size_t jj = (size_t)(strip * 4 + qr) * 512 + 2 * t;
        #pragma unroll
        for (int s = 0; s < 3; ++s) {
            const float2* src = (const float2*)(Wd3 + (jj + (size_t)s * N1) * 3); // 8B-aligned
            float2 f0 = src[0], f1 = src[1], f2 = src[2];
            w1[s][qr][0] = f0.x; w1[s][qr][1] = f0.y; w1[s][qr][2] = f1.x;
            w1[s][qr][3] = f1.y; w1[s][qr][4] = f2.x; w1[s][qr][5] = f2.y;
        }
    }
    // L2 (Wd2): rows strip*2+QR, col t; 3 floats per stream.
    float w2[3][2][3];
    #pragma unroll
    for (int QR = 0; QR < 2; ++QR) {
        const size_t jj = (size_t)(strip * 2 + QR) * 256 + t;
        #pragma unroll
        for (int s = 0; s < 3; ++s) {
            const float* src = Wd2 + (jj + (size_t)s * N2) * 3;
            w2[s][QR][0] = src[0]; w2[s][QR][1] = src[1]; w2[s][QR][2] = src[2];
        }
    }
    // L3 (Wd1 + Wa): row strip, col t>>1 — even lanes only.
    float w3[3][3] = {};
    float wa = 0.f;
    if (!(t & 1)) {
        const size_t jj = (size_t)strip * 128 + (t >> 1);
        wa = Wa[jj];
        #pragma unroll
        for (int s = 0; s < 3; ++s) {
            const float* src = Wd1 + (jj + (size_t)s * N3) * 3;
            w3[s][0] = src[0]; w3[s][1] = src[1]; w3[s][2] = src[2];
        }
    }

    // ---- image loop (verified round-0 body; sink is LDS, not global) ----
    #pragma unroll 2
    for (int bi = 0; bi < ipc; ++bi) {
        const int b = chunk * ipc + bi;
        const float* xr = x + (size_t)b * HH * WW + (size_t)strip * 8 * WW + 4 * t;

        float acc[10];
        #pragma unroll
        for (int c = 0; c < 10; ++c) acc[c] = 0.f;

        // L1: 4 row-pairs x 2 quad-cols, all thread-local.
        float a1[4][2];
        #pragma unroll
        for (int qr = 0; qr < 4; ++qr) {
            float4 u0 = *(const float4*)(xr + (size_t)(2 * qr)     * WW);
            float4 u1 = *(const float4*)(xr + (size_t)(2 * qr + 1) * WW);
            float h_[2], v_[2], d_[2];
            haar_fwd(u0.x, u0.y, u1.x, u1.y, a1[qr][0], h_[0], v_[0], d_[0]);
            haar_fwd(u0.z, u0.w, u1.z, u1.w, a1[qr][1], h_[1], v_[1], d_[1]);
            #pragma unroll
            for (int qc = 0; qc < 2; ++qc)
                #pragma unroll
                for (int c = 0; c < 3; ++c)
                    acc[7 + c] += h_[qc] * w1[0][qr][qc * 3 + c]
                                + v_[qc] * w1[1][qr][qc * 3 + c]
                                + d_[qc] * w1[2][qr][qc * 3 + c];
        }

        // L2: 2 quads, thread-local (a1 is 4 rows x 2 cols).
        float a2[2];
        #pragma unroll
        for (int QR = 0; QR < 2; ++QR) {
            float h2, v2, d2;
            haar_fwd(a1[2 * QR][0], a1[2 * QR][1], a1[2 * QR + 1][0], a1[2 * QR + 1][1],
                     a2[QR], h2, v2, d2);
            #pragma unroll
            for (int c = 0; c < 3; ++c)
                acc[4 + c] += h2 * w2[0][QR][c] + v2 * w2[1][QR][c] + d2 * w2[2][QR][c];
        }

        // L3: pair lanes t, t^1. Even lane accumulates.
        {
            float oa0 = __shfl_xor(a2[0], 1);
            float oa1 = __shfl_xor(a2[1], 1);
            if (!(t & 1)) {
                float a3, h3, v3, d3;
                haar_fwd(a2[0], oa0, a2[1], oa1, a3, h3, v3, d3);
                acc[0] += a3 * wa;
                #pragma unroll
                for (int c = 0; c < 3; ++c)
                    acc[1 + c] += h3 * w3[0][c] + v3 * w3[1][c] + d3 * w3[2][c];
            }
        }

        // Wave butterfly; lane 0 deposits the wave row into LDS.
        #pragma unroll
        for (int c = 0; c < 10; ++c) {
            float s = acc[c];
            #pragma unroll
            for (int off = 1; off < 64; off <<= 1) s += __shfl_xor(s, off);
            acc[c] = s;
        }
        if (lane == 0) {
            #pragma unroll
            for (int c = 0; c < 10; ++c) sm[bi][wave][c] = acc[c];
        }
    }

    __syncthreads();
    // tail: 10*ipc threads fold 4 waves -> channel-major global row.
    if (t < ipc * 10) {
        const int bi = t / 10, c = t - bi * 10;
        const float s = sm[bi][0][c] + sm[bi][1][c] + sm[bi][2][c] + sm[bi][3][c];
        partial[((size_t)(chunk * ipc + bi) * 10 + c) * 128 + strip] = s;
    }
}

// ---------------------------------------------------------------------------
// Kernel 2: recon with in-block gates (verified round-4 version, unchanged).
// partial is [B][10][128] channel-major: thread (c=t>>4, j=t&15), t<160,
// loads its channel's 32B run as two float4 (wave = 4 channels x 512B, fully
// coalesced, 5KB/block), 4-stage 16-lane xor reduce, lane j==0 deposits
// sums[c]; t==0 applies bias + sigmoid/softmax. The 8 x-tile float4 loads
// are pre-issued so HBM latency hides under the reduction. Recon math is the
// verified round-0 body. Grid: (128, B); 256 threads.
// ---------------------------------------------------------------------------
__global__ __launch_bounds__(256) void wa_recon(
    const float* __restrict__ x,
    const float* __restrict__ partial,   // [B, 10, 128]
    const float* __restrict__ ba,
    const float* __restrict__ bd1,
    const float* __restrict__ bd2,
    const float* __restrict__ bd3,
    float* __restrict__ out)
{
    const int strip = blockIdx.x;
    const int b = blockIdx.y;
    const int t = threadIdx.x;

    const float* xr = x + (size_t)b * HH * WW + (size_t)strip * 8 * WW + 4 * t;

    // Pre-issue the image tile loads (independent of the gate reduction).
    float4 u0[4], u1[4];
    #pragma unroll
    for (int qr = 0; qr < 4; ++qr) {
        u0[qr] = *(const float4*)(xr + (size_t)(2 * qr)     * WW);
        u1[qr] = *(const float4*)(xr + (size_t)(2 * qr + 1) * WW);
    }

    // ---- in-block gate computation ----
    __shared__ float sums[10];
    __shared__ float g[10];
    if (t < 160) {
        const int c = t >> 4, j = t & 15;
        const float4* P4 = (const float4*)(partial + ((size_t)b * 10 + c) * 128 + j * 8);
        float4 l0 = P4[0], l1 = P4[1];
        float s = ((l0.x + l0.y) + (l0.z + l0.w)) + ((l1.x + l1.y) + (l1.z + l1.w));
        s += __shfl_xor(s, 1);
        s += __shfl_xor(s, 2);
        s += __shfl_xor(s, 4);
        s += __shfl_xor(s, 8);
        if (j == 0) sums[c] = s;
    }
    __syncthreads();
    if (t == 0) {
        g[0] = 1.f / (1.f + expf(-(sums[0] + ba[0])));
        const float* bds[3] = { bd1, bd2, bd3 };
        #pragma unroll
        for (int lv = 0; lv < 3; ++lv) {
            float l0 = sums[1 + 3 * lv + 0] + bds[lv][0];
            float l1 = sums[1 + 3 * lv + 1] + bds[lv][1];
            float l2 = sums[1 + 3 * lv + 2] + bds[lv][2];
            float m = fmaxf(l0, fmaxf(l1, l2));
            float e0 = expf(l0 - m), e1 = expf(l1 - m), e2 = expf(l2 - m);
            float inv = 1.f / (e0 + e1 + e2);
            g[1 + 3 * lv + 0] = e0 * inv;
            g[1 + 3 * lv + 1] = e1 * inv;
            g[1 + 3 * lv + 2] = e2 * inv;
        }
    }
    __syncthreads();

    // ---- recon (verified round-0 body) ----
    float a1[4][2], h1[4][2], v1[4][2], d1[4][2];
    #pragma unroll
    for (int qr = 0; qr < 4; ++qr) {
        haar_fwd(u0[qr].x, u0[qr].y, u1[qr].x, u1[qr].y,
                 a1[qr][0], h1[qr][0], v1[qr][0], d1[qr][0]);
        haar_fwd(u0[qr].z, u0[qr].w, u1[qr].z, u1[qr].w,
                 a1[qr][1], h1[qr][1], v1[qr][1], d1[qr][1]);
    }
    float a2[2], h2[2], v2[2], d2[2];
    #pragma unroll
    for (int QR = 0; QR < 2; ++QR)
        haar_fwd(a1[2 * QR][0], a1[2 * QR][1], a1[2 * QR + 1][0], a1[2 * QR + 1][1],
                 a2[QR], h2[QR], v2[QR], d2[QR]);

    // L3 redundantly on both pair lanes.
    float oa0 = __shfl_xor(a2[0], 1);
    float oa1 = __shfl_xor(a2[1], 1);
    const bool rightside = t & 1;
    float a3, h3, v3, d3;
    if (!rightside) haar_fwd(a2[0], oa0, a2[1], oa1, a3, h3, v3, d3);
    else            haar_fwd(oa0, a2[0], oa1, a2[1], a3, h3, v3, d3);

    // Gate + inverse.
    a3 *= g[0];
    float P, Q, R, S;
    haar_inv(a3, h3 * g[1], v3 * g[2], d3 * g[3], P, Q, R, S);
    float r2[2];
    r2[0] = rightside ? Q : P;        // L2-approx at (QR=0, my col)
    r2[1] = rightside ? S : R;        // (QR=1, my col)

    float ra1[4][2];
    #pragma unroll
    for (int QR = 0; QR < 2; ++QR) {
        haar_inv(r2[QR], h2[QR] * g[4], v2[QR] * g[5], d2[QR] * g[6], P, Q, R, S);
        ra1[2 * QR][0] = P; ra1[2 * QR][1] = Q;
        ra1[2 * QR + 1][0] = R; ra1[2 * QR + 1][1] = S;
    }

    float* orow = out + (size_t)b * HH * WW + (size_t)strip * 8 * WW + 4 * t;
    #pragma unroll
    for (int qr = 0; qr < 4; ++qr) {
        float4 o0, o1;
        haar_inv(ra1[qr][0], h1[qr][0] * g[7], v1[qr][0] * g[8], d1[qr][0] * g[9],
                 o0.x, o0.y, o1.x, o1.y);
        haar_inv(ra1[qr][1], h1[qr][1] * g[7], v1[qr][1] * g[8], d1[qr][1] * g[9],
                 o0.z, o0.w, o1.z, o1.w);
        *(float4*)(orow + (size_t)(2 * qr)     * WW) = o0;
        *(float4*)(orow + (size_t)(2 * qr + 1) * WW) = o1;
    }
}

extern "C" void kernel_launch(void* const* d_in, const int* in_sizes, int n_in,
                              void* d_out, int out_size, void* d_ws, size_t ws_size,
                              hipStream_t stream) {
    const float* x   = (const float*)d_in[0];
    const float* Wa  = (const float*)d_in[1];
    const float* ba  = (const float*)d_in[2];
    const float* Wd1 = (const float*)d_in[3];
    const float* bd1 = (const float*)d_in[4];
    const float* Wd2 = (const float*)d_in[5];
    const float* bd2 = (const float*)d_in[6];
    const float* Wd3 = (const float*)d_in[7];
    const float* bd3 = (const float*)d_in[8];
    float* out = (float*)d_out;

    const int B = in_sizes[0] / (HH * WW);

    float* partial = (float*)d_ws;                               // [B, 10, 128]

    int nchunk = NCHUNK, ipc = B / NCHUNK;
    if (B % NCHUNK || ipc > MAX_IPC) { nchunk = B; ipc = 1; }    // safety

    dim3 fgrid(128, nchunk);
    wa_fwd_dots<<<fgrid, 256, 0, stream>>>(x, Wa, Wd1, Wd2, Wd3, partial, ipc);
    dim3 rgrid(128, B);
    wa_recon<<<rgrid, 256, 0, stream>>>(x, partial, ba, bd1, bd2, bd3, out);
}

// Round 6
// 149.320 us; speedup vs baseline: 1.0428x; 1.0428x over previous
//
#include <hip/hip_runtime.h>
#include <math.h>

// Problem constants (B derived at launch; spatial dims fixed by weight shapes).
#define HH 1024
#define WW 1024
#define N1 262144   // 512*512 per-image level-1 detail size
#define N2 65536    // 256*256
#define N3 16384    // 128*128
// NCHUNK=4 is the empirically confirmed optimum on the weight-traffic vs
// occupancy curve: NCHUNK=16 -> 217 MB fetch, 6x regression (round 2);
// NCHUNK=2 -> 1 block/CU starves the memory pipeline, +6 us (round 5).
#define NCHUNK 4           // fwd batch chunks; each block handles B/NCHUNK images
#define MAX_IPC 8          // LDS sizing bound for fwd's fold stage

#define C_INV_SQRT2 0.70710678118654752440f

static __device__ __forceinline__ void haar_fwd(float P, float Q, float R, float S,
                                                float& a, float& h, float& v, float& d) {
    // reference: split along -1 (cols) first, then -2 (rows)
    const float C = C_INV_SQRT2;
    float lo0 = (P + Q) * C, lo1 = (R + S) * C;
    float hi0 = (P - Q) * C, hi1 = (R - S) * C;
    a = (lo0 + lo1) * C; h = (lo0 - lo1) * C;
    v = (hi0 + hi1) * C; d = (hi0 - hi1) * C;
}

static __device__ __forceinline__ void haar_inv(float a, float h, float v, float d,
                                                float& P, float& Q, float& R, float& S) {
    // reference: merge along -2 (rows) first, then -1 (cols)
    // P=(r0,c0) Q=(r0,c1) R=(r1,c0) S=(r1,c1)
    const float C = C_INV_SQRT2;
    float elo = (a + h) * C, olo = (a - h) * C;
    float ehi = (v + d) * C, ohi = (v - d) * C;
    P = (elo + ehi) * C; Q = (elo - ehi) * C;
    R = (olo + ohi) * C; S = (olo - ohi) * C;
}

// ---------------------------------------------------------------------------
// Kernel 1: forward DWT + logit partials, batch-amortized weights (verified
// round-0 compute body; round-4 LDS fold + channel-major partial).
// Grid: (128 strips, NCHUNK); 256 threads. Thread t owns pixel cols
// [4t,4t+4) x 8 rows: every global load is 64 lanes x contiguous 16B = full
// 1KB lines. Strip weights live in registers, reused across the image loop.
// partial[b][c][strip], channel layout: [0]=approx, [1..3]=lvl3(Wd1),
// [4..6]=lvl2(Wd2), [7..9]=lvl1(Wd3).
// ---------------------------------------------------------------------------
__global__ __launch_bounds__(256) void wa_fwd_dots(
    const float* __restrict__ x,
    const float* __restrict__ Wa,
    const float* __restrict__ Wd1,   // [3*N3, 3] coarsest
    const float* __restrict__ Wd2,   // [3*N2, 3]
    const float* __restrict__ Wd3,   // [3*N1, 3] finest
    float* __restrict__ partial,     // [B, 10, 128] channel-major
    int ipc)                         // images per chunk
{
    const int strip = blockIdx.x;          // [0,128): pixel rows strip*8..+8
    const int chunk = blockIdx.y;
    const int t = threadIdx.x;             // L2-col index; px cols 4t..4t+3
    const int lane = t & 63, wave = t >> 6;

    __shared__ float sm[MAX_IPC][4][10];   // [image][wave][channel]

    // ---- strip weights -> registers (once per block, reused ipc times) ----
    // L1 (Wd3): rows strip*4+qr, cols 2t,2t+1; 6 floats per stream per row.
    float w1[3][4][6];
    #pragma unroll
    for (int qr = 0; qr < 4; ++qr) {
        const size_t jj = (size_t)(strip * 4 + qr) * 512 + 2 * t;
        #pragma unroll
        for (int s = 0; s < 3; ++s) {
            const float2* src = (const float2*)(Wd3 + (jj + (size_t)s * N1) * 3); // 8B-aligned
            float2 f0 = src[0], f1 = src[1], f2 = src[2];
            w1[s][qr][0] = f0.x; w1[s][qr][1] = f0.y; w1[s][qr][2] = f1.x;
            w1[s][qr][3] = f1.y; w1[s][qr][4] = f2.x; w1[s][qr][5] = f2.y;
        }
    }
    // L2 (Wd2): rows strip*2+QR, col t; 3 floats per stream.
    float w2[3][2][3];
    #pragma unroll
    for (int QR = 0; QR < 2; ++QR) {
        const size_t jj = (size_t)(strip * 2 + QR) * 256 + t;
        #pragma unroll
        for (int s = 0; s < 3; ++s) {
            const float* src = Wd2 + (jj + (size_t)s * N2) * 3;
            w2[s][QR][0] = src[0]; w2[s][QR][1] = src[1]; w2[s][QR][2] = src[2];
        }
    }
    // L3 (Wd1 + Wa): row strip, col t>>1 — even lanes only.
    float w3[3][3] = {};
    float wa = 0.f;
    if (!(t & 1)) {
        const size_t jj = (size_t)strip * 128 + (t >> 1);
        wa = Wa[jj];
        #pragma unroll
        for (int s = 0; s < 3; ++s) {
            const float* src = Wd1 + (jj + (size_t)s * N3) * 3;
            w3[s][0] = src[0]; w3[s][1] = src[1]; w3[s][2] = src[2];
        }
    }

    // ---- image loop (verified round-0 body; sink is LDS, not global) ----
    #pragma unroll 2
    for (int bi = 0; bi < ipc; ++bi) {
        const int b = chunk * ipc + bi;
        const float* xr = x + (size_t)b * HH * WW + (size_t)strip * 8 * WW + 4 * t;

        float acc[10];
        #pragma unroll
        for (int c = 0; c < 10; ++c) acc[c] = 0.f;

        // L1: 4 row-pairs x 2 quad-cols, all thread-local.
        float a1[4][2];
        #pragma unroll
        for (int qr = 0; qr < 4; ++qr) {
            float4 u0 = *(const float4*)(xr + (size_t)(2 * qr)     * WW);
            float4 u1 = *(const float4*)(xr + (size_t)(2 * qr + 1) * WW);
            float h_[2], v_[2], d_[2];
            haar_fwd(u0.x, u0.y, u1.x, u1.y, a1[qr][0], h_[0], v_[0], d_[0]);
            haar_fwd(u0.z, u0.w, u1.z, u1.w, a1[qr][1], h_[1], v_[1], d_[1]);
            #pragma unroll
            for (int qc = 0; qc < 2; ++qc)
                #pragma unroll
                for (int c = 0; c < 3; ++c)
                    acc[7 + c] += h_[qc] * w1[0][qr][qc * 3 + c]
                                + v_[qc] * w1[1][qr][qc * 3 + c]
                                + d_[qc] * w1[2][qr][qc * 3 + c];
        }

        // L2: 2 quads, thread-local (a1 is 4 rows x 2 cols).
        float a2[2];
        #pragma unroll
        for (int QR = 0; QR < 2; ++QR) {
            float h2, v2, d2;
            haar_fwd(a1[2 * QR][0], a1[2 * QR][1], a1[2 * QR + 1][0], a1[2 * QR + 1][1],
                     a2[QR], h2, v2, d2);
            #pragma unroll
            for (int c = 0; c < 3; ++c)
                acc[4 + c] += h2 * w2[0][QR][c] + v2 * w2[1][QR][c] + d2 * w2[2][QR][c];
        }

        // L3: pair lanes t, t^1. Even lane accumulates.
        {
            float oa0 = __shfl_xor(a2[0], 1);
            float oa1 = __shfl_xor(a2[1], 1);
            if (!(t & 1)) {
                float a3, h3, v3, d3;
                haar_fwd(a2[0], oa0, a2[1], oa1, a3, h3, v3, d3);
                acc[0] += a3 * wa;
                #pragma unroll
                for (int c = 0; c < 3; ++c)
                    acc[1 + c] += h3 * w3[0][c] + v3 * w3[1][c] + d3 * w3[2][c];
            }
        }

        // Wave butterfly; lane 0 deposits the wave row into LDS.
        #pragma unroll
        for (int c = 0; c < 10; ++c) {
            float s = acc[c];
            #pragma unroll
            for (int off = 1; off < 64; off <<= 1) s += __shfl_xor(s, off);
            acc[c] = s;
        }
        if (lane == 0) {
            #pragma unroll
            for (int c = 0; c < 10; ++c) sm[bi][wave][c] = acc[c];
        }
    }

    __syncthreads();
    // tail: 10*ipc threads fold 4 waves -> channel-major global row.
    if (t < ipc * 10) {
        const int bi = t / 10, c = t - bi * 10;
        const float s = sm[bi][0][c] + sm[bi][1][c] + sm[bi][2][c] + sm[bi][3][c];
        partial[((size_t)(chunk * ipc + bi) * 10 + c) * 128 + strip] = s;
    }
}

// ---------------------------------------------------------------------------
// Kernel 2: recon with in-block gates (verified round-4 version, unchanged).
// partial is [B][10][128] channel-major: thread (c=t>>4, j=t&15), t<160,
// loads its channel's 32B run as two float4 (wave = 4 channels x 512B, fully
// coalesced, 5KB/block), 4-stage 16-lane xor reduce, lane j==0 deposits
// sums[c]; t==0 applies bias + sigmoid/softmax. The 8 x-tile float4 loads
// are pre-issued so HBM latency hides under the reduction. Recon math is the
// verified round-0 body. Grid: (128, B); 256 threads.
// ---------------------------------------------------------------------------
__global__ __launch_bounds__(256) void wa_recon(
    const float* __restrict__ x,
    const float* __restrict__ partial,   // [B, 10, 128]
    const float* __restrict__ ba,
    const float* __restrict__ bd1,
    const float* __restrict__ bd2,
    const float* __restrict__ bd3,
    float* __restrict__ out)
{
    const int strip = blockIdx.x;
    const int b = blockIdx.y;
    const int t = threadIdx.x;

    const float* xr = x + (size_t)b * HH * WW + (size_t)strip * 8 * WW + 4 * t;

    // Pre-issue the image tile loads (independent of the gate reduction).
    float4 u0[4], u1[4];
    #pragma unroll
    for (int qr = 0; qr < 4; ++qr) {
        u0[qr] = *(const float4*)(xr + (size_t)(2 * qr)     * WW);
        u1[qr] = *(const float4*)(xr + (size_t)(2 * qr + 1) * WW);
    }

    // ---- in-block gate computation ----
    __shared__ float sums[10];
    __shared__ float g[10];
    if (t < 160) {
        const int c = t >> 4, j = t & 15;
        const float4* P4 = (const float4*)(partial + ((size_t)b * 10 + c) * 128 + j * 8);
        float4 l0 = P4[0], l1 = P4[1];
        float s = ((l0.x + l0.y) + (l0.z + l0.w)) + ((l1.x + l1.y) + (l1.z + l1.w));
        s += __shfl_xor(s, 1);
        s += __shfl_xor(s, 2);
        s += __shfl_xor(s, 4);
        s += __shfl_xor(s, 8);
        if (j == 0) sums[c] = s;
    }
    __syncthreads();
    if (t == 0) {
        g[0] = 1.f / (1.f + expf(-(sums[0] + ba[0])));
        const float* bds[3] = { bd1, bd2, bd3 };
        #pragma unroll
        for (int lv = 0; lv < 3; ++lv) {
            float l0 = sums[1 + 3 * lv + 0] + bds[lv][0];
            float l1 = sums[1 + 3 * lv + 1] + bds[lv][1];
            float l2 = sums[1 + 3 * lv + 2] + bds[lv][2];
            float m = fmaxf(l0, fmaxf(l1, l2));
            float e0 = expf(l0 - m), e1 = expf(l1 - m), e2 = expf(l2 - m);
            float inv = 1.f / (e0 + e1 + e2);
            g[1 + 3 * lv + 0] = e0 * inv;
            g[1 + 3 * lv + 1] = e1 * inv;
            g[1 + 3 * lv + 2] = e2 * inv;
        }
    }
    __syncthreads();

    // ---- recon (verified round-0 body) ----
    float a1[4][2], h1[4][2], v1[4][2], d1[4][2];
    #pragma unroll
    for (int qr = 0; qr < 4; ++qr) {
        haar_fwd(u0[qr].x, u0[qr].y, u1[qr].x, u1[qr].y,
                 a1[qr][0], h1[qr][0], v1[qr][0], d1[qr][0]);
        haar_fwd(u0[qr].z, u0[qr].w, u1[qr].z, u1[qr].w,
                 a1[qr][1], h1[qr][1], v1[qr][1], d1[qr][1]);
    }
    float a2[2], h2[2], v2[2], d2[2];
    #pragma unroll
    for (int QR = 0; QR < 2; ++QR)
        haar_fwd(a1[2 * QR][0], a1[2 * QR][1], a1[2 * QR + 1][0], a1[2 * QR + 1][1],
                 a2[QR], h2[QR], v2[QR], d2[QR]);

    // L3 redundantly on both pair lanes.
    float oa0 = __shfl_xor(a2[0], 1);
    float oa1 = __shfl_xor(a2[1], 1);
    const bool rightside = t & 1;
    float a3, h3, v3, d3;
    if (!rightside) haar_fwd(a2[0], oa0, a2[1], oa1, a3, h3, v3, d3);
    else            haar_fwd(oa0, a2[0], oa1, a2[1], a3, h3, v3, d3);

    // Gate + inverse.
    a3 *= g[0];
    float P, Q, R, S;
    haar_inv(a3, h3 * g[1], v3 * g[2], d3 * g[3], P, Q, R, S);
    float r2[2];
    r2[0] = rightside ? Q : P;        // L2-approx at (QR=0, my col)
    r2[1] = rightside ? S : R;        // (QR=1, my col)

    float ra1[4][2];
    #pragma unroll
    for (int QR = 0; QR < 2; ++QR) {
        haar_inv(r2[QR], h2[QR] * g[4], v2[QR] * g[5], d2[QR] * g[6], P, Q, R, S);
        ra1[2 * QR][0] = P; ra1[2 * QR][1] = Q;
        ra1[2 * QR + 1][0] = R; ra1[2 * QR + 1][1] = S;
    }

    float* orow = out + (size_t)b * HH * WW + (size_t)strip * 8 * WW + 4 * t;
    #pragma unroll
    for (int qr = 0; qr < 4; ++qr) {
        float4 o0, o1;
        haar_inv(ra1[qr][0], h1[qr][0] * g[7], v1[qr][0] * g[8], d1[qr][0] * g[9],
                 o0.x, o0.y, o1.x, o1.y);
        haar_inv(ra1[qr][1], h1[qr][1] * g[7], v1[qr][1] * g[8], d1[qr][1] * g[9],
                 o0.z, o0.w, o1.z, o1.w);
        *(float4*)(orow + (size_t)(2 * qr)     * WW) = o0;
        *(float4*)(orow + (size_t)(2 * qr + 1) * WW) = o1;
    }
}

extern "C" void kernel_launch(void* const* d_in, const int* in_sizes, int n_in,
                              void* d_out, int out_size, void* d_ws, size_t ws_size,
                              hipStream_t stream) {
    const float* x   = (const float*)d_in[0];
    const float* Wa  = (const float*)d_in[1];
    const float* ba  = (const float*)d_in[2];
    const float* Wd1 = (const float*)d_in[3];
    const float* bd1 = (const float*)d_in[4];
    const float* Wd2 = (const float*)d_in[5];
    const float* bd2 = (const float*)d_in[6];
    const float* Wd3 = (const float*)d_in[7];
    const float* bd3 = (const float*)d_in[8];
    float* out = (float*)d_out;

    const int B = in_sizes[0] / (HH * WW);

    float* partial = (float*)d_ws;                               // [B, 10, 128]

    int nchunk = NCHUNK, ipc = B / NCHUNK;
    if (B % NCHUNK || ipc > MAX_IPC) { nchunk = B; ipc = 1; }    // safety

    dim3 fgrid(128, nchunk);
    wa_fwd_dots<<<fgrid, 256, 0, stream>>>(x, Wa, Wd1, Wd2, Wd3, partial, ipc);
    dim3 rgrid(128, B);
    wa_recon<<<rgrid, 256, 0, stream>>>(x, partial, ba, bd1, bd2, bd3, out);
}